// Round 6
// baseline (947.814 us; speedup 1.0000x reference)
//
#include <hip/hip_runtime.h>

#define NUM_CODES 4096
#define CODE_DIM  64
#define NPTS      65536              // B*S = 16*4096
#define NTILES    (NUM_CODES / 16)   // 256 code tiles
#define NSEG2     8                  // code segments in scan (occupancy)
#define SEGTILES  (NTILES / NSEG2)   // 32 tiles per segment
#define DECAYF    0.99f
#define EPSF      1e-5f
#define THRF      0.02f              // certify threshold (MFMA err bound ~3e-3)

typedef __attribute__((ext_vector_type(8))) short short8v;
typedef __attribute__((ext_vector_type(4))) float f32x4;
#define MFMA16 __builtin_amdgcn_mfma_f32_16x16x32_bf16

// ---------------- workspace layout (float indices) ----------------
#define WS_BC   0                    // 4096    batch_cluster acc
#define WS_ES   4096                 // 262144  embed_sum acc
#define WS_N    266240               // 1       n acc (float)
#define WS_CNT  266241               // 1       flagged count (int)
#define WS_CSQ  266244               // 4096    codebook sq-norms (16B aligned)
#define WS_CF   270340               // 262144  floats = A-frag codebook (bf16 hi/lo)
#define WS_TOP2 532484               // 65536*NSEG2 float4
// flagged list overlays WS_CF (dead after scan): 65536 ints fit in 262144 floats

// ---------------- output layout ----------------
#define OUT_Q    0
#define OUT_IDX  4194304
#define OUT_CB   4259840
#define OUT_CS   4521984
#define OUT_EMA  4526080

__device__ __forceinline__ unsigned short f2bf(float f) {
    unsigned u = __float_as_uint(f);
    u += 0x7FFFu + ((u >> 16) & 1u);
    return (unsigned short)(u >> 16);
}
__device__ __forceinline__ float bf2f(unsigned short h) {
    return __uint_as_float(((unsigned)h) << 16);
}

// ---------- codebook sq-norms + bf16 hi/lo A-fragment layout (merged) ----------
// cf[ctile][frag][lane][8 shorts], frag: 0=hi k0, 1=hi k1, 2=lo k0, 3=lo k1.
// A-frag (16x16x32): lane holds A[row=lane&15][k=(lane>>4)*8 + j].
__global__ __launch_bounds__(256) void prep_all(const float* __restrict__ cb,
                                                float* __restrict__ csq,
                                                short* __restrict__ cf) {
    int k = blockIdx.x * 256 + threadIdx.x;   // 4096 threads, one code row each
    const float4* cp = (const float4*)(cb + (size_t)k * CODE_DIM);
    float rowf[64];
    float s0 = 0.f, s1 = 0.f, s2 = 0.f, s3 = 0.f;
#pragma unroll
    for (int j = 0; j < 16; ++j) {
        float4 v = cp[j];
        rowf[4*j] = v.x; rowf[4*j+1] = v.y; rowf[4*j+2] = v.z; rowf[4*j+3] = v.w;
        s0 = fmaf(v.x, v.x, s0);
        s1 = fmaf(v.y, v.y, s1);
        s2 = fmaf(v.z, v.z, s2);
        s3 = fmaf(v.w, v.w, s3);
    }
    csq[k] = (s0 + s1) + (s2 + s3);

    int ctile = k >> 4;
    int r     = k & 15;
#pragma unroll
    for (int h = 0; h < 2; ++h) {
#pragma unroll
        for (int g = 0; g < 4; ++g) {
            int lane = g * 16 + r;
            short8v H, L;
#pragma unroll
            for (int j = 0; j < 8; ++j) {
                float s = -2.0f * rowf[h * 32 + g * 8 + j];
                unsigned short hb = f2bf(s);
                H[j] = (short)hb;
                L[j] = (short)f2bf(s - bf2f(hb));
            }
            *(short8v*)(cf + ((size_t)(ctile * 4 + h) * 64 + lane) * 8)     = H;
            *(short8v*)(cf + ((size_t)(ctile * 4 + 2 + h) * 64 + lane) * 8) = L;
        }
    }
}

// ---------- MFMA scan: block = 4 waves = 4 code-segments of one 64-pt group ----------
__global__ __launch_bounds__(256, 6) void scan_mfma(const float* __restrict__ x,
                                                    const short* __restrict__ cf,
                                                    const float* __restrict__ csq,
                                                    float4* __restrict__ top2) {
    const int wid  = threadIdx.x >> 6;           // 0..3
    const int lane = threadIdx.x & 63;
    const int blk  = blockIdx.x;                 // 0..2047
    const int pw   = blk >> 1;                   // point group 0..1023
    const int seg  = (blk & 1) * 4 + wid;        // 0..7
    const int col  = lane & 15;
    const int grp  = lane >> 4;
    const int pbase = pw * 64;

    // B-frags for 64 points, bf16 hi/lo split in-register.
    // B-frag (16x16x32): lane holds B[k=(lane>>4)*8 + j][col=lane&15].
    short8v xh[4][2], xl[4][2];
#pragma unroll
    for (int t = 0; t < 4; ++t) {
#pragma unroll
        for (int h = 0; h < 2; ++h) {
            const float* xp = x + (size_t)(pbase + t * 16 + col) * CODE_DIM + h * 32 + grp * 8;
            float4 v0 = *(const float4*)(xp);
            float4 v1 = *(const float4*)(xp + 4);
            float f[8] = {v0.x, v0.y, v0.z, v0.w, v1.x, v1.y, v1.z, v1.w};
            short8v H, L;
#pragma unroll
            for (int j = 0; j < 8; ++j) {
                unsigned short hb = f2bf(f[j]);
                H[j] = (short)hb;
                L[j] = (short)f2bf(f[j] - bf2f(hb));
            }
            xh[t][h] = H; xl[t][h] = L;
        }
    }

    float m1[4], m2[4];
    int   i1[4];
#pragma unroll
    for (int t = 0; t < 4; ++t) { m1[t] = 3e38f; m2[t] = 3e38f; i1[t] = 0; }

#define LOAD_TILE(CT, AF, CQ) do { \
    const short* p_ = cf + ((size_t)(CT) * 4 * 64 + lane) * 8; \
    AF[0] = *(const short8v*)(p_); \
    AF[1] = *(const short8v*)(p_ + 64 * 8); \
    AF[2] = *(const short8v*)(p_ + 2 * 64 * 8); \
    AF[3] = *(const short8v*)(p_ + 3 * 64 * 8); \
    CQ = *(const float4*)(csq + (CT) * 16 + grp * 4); } while(0)

#define COMPUTE_TILE(CT, AF, CQ) do { \
    const int cbase_ = (CT) * 16 + grp * 4; \
    _Pragma("unroll") \
    for (int t = 0; t < 4; ++t) { \
        f32x4 a; a[0] = CQ.x; a[1] = CQ.y; a[2] = CQ.z; a[3] = CQ.w; \
        a = MFMA16(AF[0], xh[t][0], a, 0, 0, 0); \
        a = MFMA16(AF[1], xh[t][1], a, 0, 0, 0); \
        a = MFMA16(AF[0], xl[t][0], a, 0, 0, 0); \
        a = MFMA16(AF[1], xl[t][1], a, 0, 0, 0); \
        a = MFMA16(AF[2], xh[t][0], a, 0, 0, 0); \
        a = MFMA16(AF[3], xh[t][1], a, 0, 0, 0); \
        _Pragma("unroll") \
        for (int r = 0; r < 4; ++r) { \
            float k_ = a[r]; \
            bool lt_ = k_ < m1[t]; \
            float nm2_ = __builtin_amdgcn_fmed3f(m1[t], m2[t], k_); \
            i1[t] = lt_ ? (cbase_ + r) : i1[t]; \
            m1[t] = fminf(m1[t], k_); \
            m2[t] = nm2_; \
        } \
    } } while(0)

    short8v A0[4], A1[4];
    float4 q0, q1;
    const int tb = seg * SEGTILES;
    LOAD_TILE(tb, A0, q0);
#pragma unroll 4
    for (int it = 0; it < SEGTILES / 2; ++it) {
        const int t0 = tb + 2 * it, t1 = t0 + 1;
        const int t2 = (2 * it + 2 < SEGTILES) ? t1 + 1 : tb;
        LOAD_TILE(t1, A1, q1);
        COMPUTE_TILE(t0, A0, q0);
        LOAD_TILE(t2, A0, q0);
        COMPUTE_TILE(t1, A1, q1);
    }
#undef LOAD_TILE
#undef COMPUTE_TILE

    // cross-lane merge: lanes l, l^16, l^32 hold disjoint code subsets of point col
#pragma unroll
    for (int t = 0; t < 4; ++t) {
#pragma unroll
        for (int off = 16; off <= 32; off <<= 1) {
            float om1 = __shfl_xor(m1[t], off);
            int   oi1 = __shfl_xor(i1[t], off);
            float om2 = __shfl_xor(m2[t], off);
            float nm2 = fminf(fmaxf(m1[t], om1), fminf(m2[t], om2));
            bool take = (om1 < m1[t]) || (om1 == m1[t] && oi1 < i1[t]);
            i1[t] = take ? oi1 : i1[t];
            m1[t] = fminf(m1[t], om1);
            m2[t] = nm2;
        }
    }
    if (lane < 16) {
#pragma unroll
        for (int t = 0; t < 4; ++t) {
            top2[(size_t)(pbase + t * 16 + lane) * NSEG2 + seg] =
                make_float4(m1[t], __int_as_float(i1[t]), m2[t], 0.0f);
        }
    }
}

// ---------- merge segments; certify or flag (wave-aggregated append) ----------
__global__ __launch_bounds__(256) void emit1(const float4* __restrict__ top2,
                                             float* __restrict__ idx_out,
                                             float* __restrict__ bc_acc,
                                             int* __restrict__ flagged,
                                             int* __restrict__ cnt) {
    const int p = blockIdx.x * 256 + threadIdx.x;
    const int lane = threadIdx.x & 63;
    const float4* tp = top2 + (size_t)p * NSEG2;
    float4 t0 = tp[0];
    float m1 = t0.x; int i1 = __float_as_int(t0.y); float m2 = t0.z;
#pragma unroll
    for (int s = 1; s < NSEG2; ++s) {
        float4 t = tp[s];
        float om1 = t.x; int oi1 = __float_as_int(t.y); float om2 = t.z;
        float nm2 = fminf(fmaxf(m1, om1), fminf(m2, om2));
        bool take = (om1 < m1) || (om1 == m1 && oi1 < i1);
        if (take) i1 = oi1;
        m1 = fminf(m1, om1);
        m2 = nm2;
    }
    bool certified = (m2 - m1 >= THRF);
    if (certified) {
        idx_out[p] = (float)i1;
        atomicAdd(&bc_acc[i1], 1.0f);
    }
    // wave-aggregated flagged append: one cnt atomic per wave
    unsigned long long mask = __ballot(!certified);
    int nw = __popcll(mask);
    int base = 0;
    if (lane == 0 && nw) base = atomicAdd(cnt, nw);
    base = __shfl(base, 0);
    if (!certified) {
        int off = __popcll(mask & ((1ULL << lane) - 1ULL));
        flagged[base + off] = p;
    }
}

// ---------- exact f64 full rescan for uncertified points (wave per point) ----------
__global__ __launch_bounds__(64) void fallback_kernel(const float* __restrict__ x,
                                                      const float* __restrict__ cb,
                                                      const int* __restrict__ flagged,
                                                      const int* __restrict__ cnt,
                                                      float* __restrict__ idx_out,
                                                      float* __restrict__ bc_acc) {
    __shared__ float xs[CODE_DIM];
    const int lane = threadIdx.x;
    const int n = *cnt;
    for (int w = blockIdx.x; w < n; w += 1024) {
        const int p = flagged[w];
        xs[lane] = x[(size_t)p * CODE_DIM + lane];
        __syncthreads();
        float4 xv[16];
#pragma unroll
        for (int q = 0; q < 16; ++q) xv[q] = *(const float4*)(xs + q * 4);
        double best = 1e300; int bi = 0;
        for (int j = 0; j < 64; ++j) {
            const int c = lane + 64 * j;   // ascending per lane
            const float4* cp = (const float4*)(cb + (size_t)c * CODE_DIM);
            double a0 = 0.0, a1 = 0.0, a2 = 0.0, a3 = 0.0;
#pragma unroll
            for (int q = 0; q < 16; ++q) {
                float4 cv = cp[q];
                double d0 = (double)xv[q].x - (double)cv.x;
                double d1 = (double)xv[q].y - (double)cv.y;
                double d2 = (double)xv[q].z - (double)cv.z;
                double d3 = (double)xv[q].w - (double)cv.w;
                a0 = fma(d0, d0, a0);
                a1 = fma(d1, d1, a1);
                a2 = fma(d2, d2, a2);
                a3 = fma(d3, d3, a3);
            }
            double acc = (a0 + a1) + (a2 + a3);
            if (acc < best) { best = acc; bi = c; }
        }
#pragma unroll
        for (int off = 1; off < 64; off <<= 1) {
            double ob = __shfl_xor(best, off);
            int   obi = __shfl_xor(bi, off);
            if (ob < best || (ob == best && obi < bi)) { best = ob; bi = obi; }
        }
        if (lane == 0) {
            idx_out[p] = (float)bi;
            atomicAdd(&bc_acc[bi], 1.0f);
        }
        __syncthreads();
    }
}

// ---------- quantized write + embed_sum scatter: one wave per point ----------
__global__ __launch_bounds__(256) void emit2(const float* __restrict__ x,
                                             const float* __restrict__ cb,
                                             const float* __restrict__ idx_out,
                                             float* __restrict__ q_out,
                                             float* __restrict__ es_acc) {
    const int p    = blockIdx.x * 4 + (threadIdx.x >> 6);
    const int lane = threadIdx.x & 63;
    const int fin  = (int)idx_out[p];
    float xv = x[(size_t)p * CODE_DIM + lane];
    float cv = cb[(size_t)fin * CODE_DIM + lane];
    q_out[(size_t)p * CODE_DIM + lane] = cv;
    atomicAdd(&es_acc[(size_t)fin * CODE_DIM + lane], xv);
}

__global__ __launch_bounds__(256) void ncs_kernel(const float* __restrict__ cs_in,
                                                  const float* __restrict__ bc_acc,
                                                  float* __restrict__ cs_out,
                                                  float* __restrict__ n_acc) {
    int k = blockIdx.x * 256 + threadIdx.x;   // 4096 threads
    float v = DECAYF * cs_in[k] + (1.0f - DECAYF) * bc_acc[k];
    cs_out[k] = v;
    float s = v;
#pragma unroll
    for (int off = 32; off > 0; off >>= 1) s += __shfl_down(s, off);
    if ((threadIdx.x & 63) == 0) atomicAdd(n_acc, s);
}

__global__ __launch_bounds__(256) void finalize_kernel(const float* __restrict__ ema_in,
                                                       const float* __restrict__ es_acc,
                                                       const float* __restrict__ cs_out,
                                                       const float* __restrict__ n_acc,
                                                       float* __restrict__ ema_out,
                                                       float* __restrict__ cb_out) {
    int idx = blockIdx.x * 256 + threadIdx.x;   // 262144 threads
    int k   = idx >> 6;
    float n = *n_acc;
    float ncs = cs_out[k];
    float smoothed = (ncs + EPSF) / (n + (float)NUM_CODES * EPSF) * n;
    float ew = DECAYF * ema_in[idx] + (1.0f - DECAYF) * es_acc[idx];
    ema_out[idx] = ew;
    cb_out[idx]  = ew / smoothed;
}

extern "C" void kernel_launch(void* const* d_in, const int* in_sizes, int n_in,
                              void* d_out, int out_size, void* d_ws, size_t ws_size,
                              hipStream_t stream) {
    const float* x    = (const float*)d_in[0];
    const float* cb   = (const float*)d_in[1];
    const float* cs   = (const float*)d_in[2];
    const float* emaw = (const float*)d_in[3];
    float* out = (float*)d_out;
    float* ws  = (float*)d_ws;

    // zero bc + es + n + cnt (contiguous)
    hipMemsetAsync(ws, 0, (size_t)(WS_CNT + 1) * sizeof(float), stream);

    prep_all<<<NUM_CODES / 256, 256, 0, stream>>>(cb, ws + WS_CSQ, (short*)(ws + WS_CF));

    scan_mfma<<<(NPTS / 64) * NSEG2 / 4, 256, 0, stream>>>(
        x, (const short*)(ws + WS_CF), ws + WS_CSQ, (float4*)(ws + WS_TOP2));

    emit1<<<NPTS / 256, 256, 0, stream>>>(
        (const float4*)(ws + WS_TOP2), out + OUT_IDX, ws + WS_BC,
        (int*)(ws + WS_CF), (int*)(ws + WS_CNT));

    fallback_kernel<<<1024, 64, 0, stream>>>(
        x, cb, (const int*)(ws + WS_CF), (const int*)(ws + WS_CNT),
        out + OUT_IDX, ws + WS_BC);

    emit2<<<NPTS / 4, 256, 0, stream>>>(
        x, cb, out + OUT_IDX, out + OUT_Q, ws + WS_ES);

    ncs_kernel<<<NUM_CODES / 256, 256, 0, stream>>>(
        cs, ws + WS_BC, out + OUT_CS, ws + WS_N);

    finalize_kernel<<<(NUM_CODES * CODE_DIM) / 256, 256, 0, stream>>>(
        emaw, ws + WS_ES, out + OUT_CS, ws + WS_N, out + OUT_EMA, out + OUT_CB);
}

// Round 7
// 485.329 us; speedup vs baseline: 1.9529x; 1.9529x over previous
//
#include <hip/hip_runtime.h>

#define NUM_CODES 4096
#define CODE_DIM  64
#define NPTS      65536              // B*S = 16*4096
#define NTILES    (NUM_CODES / 16)   // 256 code tiles
#define NSEG2     8                  // code segments in scan (occupancy)
#define SEGTILES  (NTILES / NSEG2)   // 32 tiles per segment
#define DECAYF    0.99f
#define EPSF      1e-5f
#define THRF      0.02f              // certify threshold (MFMA err bound ~3e-3)

typedef __attribute__((ext_vector_type(8))) short short8v;
typedef __attribute__((ext_vector_type(4))) float f32x4;
#define MFMA16 __builtin_amdgcn_mfma_f32_16x16x32_bf16

// ---------------- workspace layout (float indices) ----------------
#define WS_BC   0                    // 4096    batch_cluster acc
#define WS_ES   4096                 // 262144  embed_sum acc
#define WS_N    266240               // 1       n acc (float)
#define WS_CNT  266241               // 1       flagged count (int)
#define WS_CSQ  266244               // 4096    codebook sq-norms (16B aligned)
#define WS_CF   270340               // 262144  floats = A-frag codebook (bf16 hi/lo)
#define WS_TOP2 532484               // 65536*NSEG2 float4
// flagged list overlays WS_CF (dead after scan): 65536 ints fit in 262144 floats

// ---------------- output layout ----------------
#define OUT_Q    0
#define OUT_IDX  4194304
#define OUT_CB   4259840
#define OUT_CS   4521984
#define OUT_EMA  4526080

__device__ __forceinline__ unsigned short f2bf(float f) {
    unsigned u = __float_as_uint(f);
    u += 0x7FFFu + ((u >> 16) & 1u);
    return (unsigned short)(u >> 16);
}
__device__ __forceinline__ float bf2f(unsigned short h) {
    return __uint_as_float(((unsigned)h) << 16);
}

// ---------- codebook sq-norms + bf16 hi/lo A-fragment layout (merged) ----------
// cf[ctile][frag][lane][8 shorts], frag: 0=hi k0, 1=hi k1, 2=lo k0, 3=lo k1.
// A-frag (16x16x32): lane holds A[row=lane&15][k=(lane>>4)*8 + j].
__global__ __launch_bounds__(256) void prep_all(const float* __restrict__ cb,
                                                float* __restrict__ csq,
                                                short* __restrict__ cf) {
    int k = blockIdx.x * 256 + threadIdx.x;   // 4096 threads, one code row each
    const float4* cp = (const float4*)(cb + (size_t)k * CODE_DIM);
    float rowf[64];
    float s0 = 0.f, s1 = 0.f, s2 = 0.f, s3 = 0.f;
#pragma unroll
    for (int j = 0; j < 16; ++j) {
        float4 v = cp[j];
        rowf[4*j] = v.x; rowf[4*j+1] = v.y; rowf[4*j+2] = v.z; rowf[4*j+3] = v.w;
        s0 = fmaf(v.x, v.x, s0);
        s1 = fmaf(v.y, v.y, s1);
        s2 = fmaf(v.z, v.z, s2);
        s3 = fmaf(v.w, v.w, s3);
    }
    csq[k] = (s0 + s1) + (s2 + s3);

    int ctile = k >> 4;
    int r     = k & 15;
#pragma unroll
    for (int h = 0; h < 2; ++h) {
#pragma unroll
        for (int g = 0; g < 4; ++g) {
            int lane = g * 16 + r;
            short8v H, L;
#pragma unroll
            for (int j = 0; j < 8; ++j) {
                float s = -2.0f * rowf[h * 32 + g * 8 + j];
                unsigned short hb = f2bf(s);
                H[j] = (short)hb;
                L[j] = (short)f2bf(s - bf2f(hb));
            }
            *(short8v*)(cf + ((size_t)(ctile * 4 + h) * 64 + lane) * 8)     = H;
            *(short8v*)(cf + ((size_t)(ctile * 4 + 2 + h) * 64 + lane) * 8) = L;
        }
    }
}

// ---------- MFMA scan: block = 4 waves = 4 code-segments of one 64-pt group ----------
// NOTE: min-waves bound of 6 (round 6) capped VGPR at ~85 < ~110 working set ->
// compiler spilled ~3GB/dispatch to scratch. (256,4) caps at 128 VGPR: no spill.
__global__ __launch_bounds__(256, 4) void scan_mfma(const float* __restrict__ x,
                                                    const short* __restrict__ cf,
                                                    const float* __restrict__ csq,
                                                    float4* __restrict__ top2) {
    const int wid  = threadIdx.x >> 6;           // 0..3
    const int lane = threadIdx.x & 63;
    const int blk  = blockIdx.x;                 // 0..2047
    const int pw   = blk >> 1;                   // point group 0..1023
    const int seg  = (blk & 1) * 4 + wid;        // 0..7
    const int col  = lane & 15;
    const int grp  = lane >> 4;
    const int pbase = pw * 64;

    // B-frags for 64 points, bf16 hi/lo split in-register.
    // B-frag (16x16x32): lane holds B[k=(lane>>4)*8 + j][col=lane&15].
    short8v xh[4][2], xl[4][2];
#pragma unroll
    for (int t = 0; t < 4; ++t) {
#pragma unroll
        for (int h = 0; h < 2; ++h) {
            const float* xp = x + (size_t)(pbase + t * 16 + col) * CODE_DIM + h * 32 + grp * 8;
            float4 v0 = *(const float4*)(xp);
            float4 v1 = *(const float4*)(xp + 4);
            float f[8] = {v0.x, v0.y, v0.z, v0.w, v1.x, v1.y, v1.z, v1.w};
            short8v H, L;
#pragma unroll
            for (int j = 0; j < 8; ++j) {
                unsigned short hb = f2bf(f[j]);
                H[j] = (short)hb;
                L[j] = (short)f2bf(f[j] - bf2f(hb));
            }
            xh[t][h] = H; xl[t][h] = L;
        }
    }

    float m1[4], m2[4];
    int   i1[4];
#pragma unroll
    for (int t = 0; t < 4; ++t) { m1[t] = 3e38f; m2[t] = 3e38f; i1[t] = 0; }

#define LOAD_TILE(CT, AF, CQ) do { \
    const short* p_ = cf + ((size_t)(CT) * 4 * 64 + lane) * 8; \
    AF[0] = *(const short8v*)(p_); \
    AF[1] = *(const short8v*)(p_ + 64 * 8); \
    AF[2] = *(const short8v*)(p_ + 2 * 64 * 8); \
    AF[3] = *(const short8v*)(p_ + 3 * 64 * 8); \
    CQ = *(const float4*)(csq + (CT) * 16 + grp * 4); } while(0)

#define COMPUTE_TILE(CT, AF, CQ) do { \
    const int cbase_ = (CT) * 16 + grp * 4; \
    _Pragma("unroll") \
    for (int t = 0; t < 4; ++t) { \
        f32x4 a; a[0] = CQ.x; a[1] = CQ.y; a[2] = CQ.z; a[3] = CQ.w; \
        a = MFMA16(AF[0], xh[t][0], a, 0, 0, 0); \
        a = MFMA16(AF[1], xh[t][1], a, 0, 0, 0); \
        a = MFMA16(AF[0], xl[t][0], a, 0, 0, 0); \
        a = MFMA16(AF[1], xl[t][1], a, 0, 0, 0); \
        a = MFMA16(AF[2], xh[t][0], a, 0, 0, 0); \
        a = MFMA16(AF[3], xh[t][1], a, 0, 0, 0); \
        _Pragma("unroll") \
        for (int r = 0; r < 4; ++r) { \
            float k_ = a[r]; \
            bool lt_ = k_ < m1[t]; \
            float nm2_ = __builtin_amdgcn_fmed3f(m1[t], m2[t], k_); \
            i1[t] = lt_ ? (cbase_ + r) : i1[t]; \
            m1[t] = fminf(m1[t], k_); \
            m2[t] = nm2_; \
        } \
    } } while(0)

    short8v A0[4], A1[4];
    float4 q0, q1;
    const int tb = seg * SEGTILES;
    LOAD_TILE(tb, A0, q0);
#pragma unroll 4
    for (int it = 0; it < SEGTILES / 2; ++it) {
        const int t0 = tb + 2 * it, t1 = t0 + 1;
        const int t2 = (2 * it + 2 < SEGTILES) ? t1 + 1 : tb;
        LOAD_TILE(t1, A1, q1);
        COMPUTE_TILE(t0, A0, q0);
        LOAD_TILE(t2, A0, q0);
        COMPUTE_TILE(t1, A1, q1);
    }
#undef LOAD_TILE
#undef COMPUTE_TILE

    // cross-lane merge: lanes l, l^16, l^32 hold disjoint code subsets of point col
#pragma unroll
    for (int t = 0; t < 4; ++t) {
#pragma unroll
        for (int off = 16; off <= 32; off <<= 1) {
            float om1 = __shfl_xor(m1[t], off);
            int   oi1 = __shfl_xor(i1[t], off);
            float om2 = __shfl_xor(m2[t], off);
            float nm2 = fminf(fmaxf(m1[t], om1), fminf(m2[t], om2));
            bool take = (om1 < m1[t]) || (om1 == m1[t] && oi1 < i1[t]);
            i1[t] = take ? oi1 : i1[t];
            m1[t] = fminf(m1[t], om1);
            m2[t] = nm2;
        }
    }
    if (lane < 16) {
#pragma unroll
        for (int t = 0; t < 4; ++t) {
            top2[(size_t)(pbase + t * 16 + lane) * NSEG2 + seg] =
                make_float4(m1[t], __int_as_float(i1[t]), m2[t], 0.0f);
        }
    }
}

// ---------- merge segments; certify or flag (wave-aggregated append) ----------
__global__ __launch_bounds__(256) void emit1(const float4* __restrict__ top2,
                                             float* __restrict__ idx_out,
                                             float* __restrict__ bc_acc,
                                             int* __restrict__ flagged,
                                             int* __restrict__ cnt) {
    const int p = blockIdx.x * 256 + threadIdx.x;
    const int lane = threadIdx.x & 63;
    const float4* tp = top2 + (size_t)p * NSEG2;
    float4 t0 = tp[0];
    float m1 = t0.x; int i1 = __float_as_int(t0.y); float m2 = t0.z;
#pragma unroll
    for (int s = 1; s < NSEG2; ++s) {
        float4 t = tp[s];
        float om1 = t.x; int oi1 = __float_as_int(t.y); float om2 = t.z;
        float nm2 = fminf(fmaxf(m1, om1), fminf(m2, om2));
        bool take = (om1 < m1) || (om1 == m1 && oi1 < i1);
        if (take) i1 = oi1;
        m1 = fminf(m1, om1);
        m2 = nm2;
    }
    bool certified = (m2 - m1 >= THRF);
    if (certified) {
        idx_out[p] = (float)i1;
        atomicAdd(&bc_acc[i1], 1.0f);
    }
    // wave-aggregated flagged append: one cnt atomic per wave
    unsigned long long mask = __ballot(!certified);
    int nw = __popcll(mask);
    int base = 0;
    if (lane == 0 && nw) base = atomicAdd(cnt, nw);
    base = __shfl(base, 0);
    if (!certified) {
        int off = __popcll(mask & ((1ULL << lane) - 1ULL));
        flagged[base + off] = p;
    }
}

// ---------- exact f64 full rescan for uncertified points (wave per point) ----------
__global__ __launch_bounds__(64) void fallback_kernel(const float* __restrict__ x,
                                                      const float* __restrict__ cb,
                                                      const int* __restrict__ flagged,
                                                      const int* __restrict__ cnt,
                                                      float* __restrict__ idx_out,
                                                      float* __restrict__ bc_acc) {
    __shared__ float xs[CODE_DIM];
    const int lane = threadIdx.x;
    const int n = *cnt;
    for (int w = blockIdx.x; w < n; w += 1024) {
        const int p = flagged[w];
        xs[lane] = x[(size_t)p * CODE_DIM + lane];
        __syncthreads();
        float4 xv[16];
#pragma unroll
        for (int q = 0; q < 16; ++q) xv[q] = *(const float4*)(xs + q * 4);
        double best = 1e300; int bi = 0;
        for (int j = 0; j < 64; ++j) {
            const int c = lane + 64 * j;   // ascending per lane
            const float4* cp = (const float4*)(cb + (size_t)c * CODE_DIM);
            double a0 = 0.0, a1 = 0.0, a2 = 0.0, a3 = 0.0;
#pragma unroll
            for (int q = 0; q < 16; ++q) {
                float4 cv = cp[q];
                double d0 = (double)xv[q].x - (double)cv.x;
                double d1 = (double)xv[q].y - (double)cv.y;
                double d2 = (double)xv[q].z - (double)cv.z;
                double d3 = (double)xv[q].w - (double)cv.w;
                a0 = fma(d0, d0, a0);
                a1 = fma(d1, d1, a1);
                a2 = fma(d2, d2, a2);
                a3 = fma(d3, d3, a3);
            }
            double acc = (a0 + a1) + (a2 + a3);
            if (acc < best) { best = acc; bi = c; }
        }
#pragma unroll
        for (int off = 1; off < 64; off <<= 1) {
            double ob = __shfl_xor(best, off);
            int   obi = __shfl_xor(bi, off);
            if (ob < best || (ob == best && obi < bi)) { best = ob; bi = obi; }
        }
        if (lane == 0) {
            idx_out[p] = (float)bi;
            atomicAdd(&bc_acc[bi], 1.0f);
        }
        __syncthreads();
    }
}

// ---------- quantized write + embed_sum scatter: one wave per point ----------
__global__ __launch_bounds__(256) void emit2(const float* __restrict__ x,
                                             const float* __restrict__ cb,
                                             const float* __restrict__ idx_out,
                                             float* __restrict__ q_out,
                                             float* __restrict__ es_acc) {
    const int p    = blockIdx.x * 4 + (threadIdx.x >> 6);
    const int lane = threadIdx.x & 63;
    const int fin  = (int)idx_out[p];
    float xv = x[(size_t)p * CODE_DIM + lane];
    float cv = cb[(size_t)fin * CODE_DIM + lane];
    q_out[(size_t)p * CODE_DIM + lane] = cv;
    atomicAdd(&es_acc[(size_t)fin * CODE_DIM + lane], xv);
}

__global__ __launch_bounds__(256) void ncs_kernel(const float* __restrict__ cs_in,
                                                  const float* __restrict__ bc_acc,
                                                  float* __restrict__ cs_out,
                                                  float* __restrict__ n_acc) {
    int k = blockIdx.x * 256 + threadIdx.x;   // 4096 threads
    float v = DECAYF * cs_in[k] + (1.0f - DECAYF) * bc_acc[k];
    cs_out[k] = v;
    float s = v;
#pragma unroll
    for (int off = 32; off > 0; off >>= 1) s += __shfl_down(s, off);
    if ((threadIdx.x & 63) == 0) atomicAdd(n_acc, s);
}

__global__ __launch_bounds__(256) void finalize_kernel(const float* __restrict__ ema_in,
                                                       const float* __restrict__ es_acc,
                                                       const float* __restrict__ cs_out,
                                                       const float* __restrict__ n_acc,
                                                       float* __restrict__ ema_out,
                                                       float* __restrict__ cb_out) {
    int idx = blockIdx.x * 256 + threadIdx.x;   // 262144 threads
    int k   = idx >> 6;
    float n = *n_acc;
    float ncs = cs_out[k];
    float smoothed = (ncs + EPSF) / (n + (float)NUM_CODES * EPSF) * n;
    float ew = DECAYF * ema_in[idx] + (1.0f - DECAYF) * es_acc[idx];
    ema_out[idx] = ew;
    cb_out[idx]  = ew / smoothed;
}

extern "C" void kernel_launch(void* const* d_in, const int* in_sizes, int n_in,
                              void* d_out, int out_size, void* d_ws, size_t ws_size,
                              hipStream_t stream) {
    const float* x    = (const float*)d_in[0];
    const float* cb   = (const float*)d_in[1];
    const float* cs   = (const float*)d_in[2];
    const float* emaw = (const float*)d_in[3];
    float* out = (float*)d_out;
    float* ws  = (float*)d_ws;

    // zero bc + es + n + cnt (contiguous)
    hipMemsetAsync(ws, 0, (size_t)(WS_CNT + 1) * sizeof(float), stream);

    prep_all<<<NUM_CODES / 256, 256, 0, stream>>>(cb, ws + WS_CSQ, (short*)(ws + WS_CF));

    scan_mfma<<<(NPTS / 64) * NSEG2 / 4, 256, 0, stream>>>(
        x, (const short*)(ws + WS_CF), ws + WS_CSQ, (float4*)(ws + WS_TOP2));

    emit1<<<NPTS / 256, 256, 0, stream>>>(
        (const float4*)(ws + WS_TOP2), out + OUT_IDX, ws + WS_BC,
        (int*)(ws + WS_CF), (int*)(ws + WS_CNT));

    fallback_kernel<<<1024, 64, 0, stream>>>(
        x, cb, (const int*)(ws + WS_CF), (const int*)(ws + WS_CNT),
        out + OUT_IDX, ws + WS_BC);

    emit2<<<NPTS / 4, 256, 0, stream>>>(
        x, cb, out + OUT_IDX, out + OUT_Q, ws + WS_ES);

    ncs_kernel<<<NUM_CODES / 256, 256, 0, stream>>>(
        cs, ws + WS_BC, out + OUT_CS, ws + WS_N);

    finalize_kernel<<<(NUM_CODES * CODE_DIM) / 256, 256, 0, stream>>>(
        emaw, ws + WS_ES, out + OUT_CS, ws + WS_N, out + OUT_EMA, out + OUT_CB);
}

// Round 8
// 333.035 us; speedup vs baseline: 2.8460x; 1.4573x over previous
//
#include <hip/hip_runtime.h>

#define NUM_CODES 4096
#define CODE_DIM  64
#define NPTS      65536              // B*S = 16*4096
#define NTILES    (NUM_CODES / 16)   // 256 code tiles
#define NSEG2     8                  // code segments in scan (occupancy)
#define SEGTILES  (NTILES / NSEG2)   // 32 tiles per segment
#define DECAYF    0.99f
#define EPSF      1e-5f
#define THRF      0.02f              // certify threshold (MFMA err bound ~3e-3)

typedef __attribute__((ext_vector_type(8))) short short8v;
typedef __attribute__((ext_vector_type(4))) float f32x4;
#define MFMA16 __builtin_amdgcn_mfma_f32_16x16x32_bf16

// ---------------- workspace layout (float indices) ----------------
#define WS_BC   0                    // 4096    batch_cluster acc
#define WS_ES   4096                 // 262144  embed_sum acc
#define WS_N    266240               // 1       n acc (float)
#define WS_CNT  266241               // 1       flagged count (int)
#define WS_CSQ  266244               // 4096    codebook sq-norms (16B aligned)
#define WS_CF   270340               // 262144  floats = A-frag codebook (bf16 hi/lo)
#define WS_TOP2 532484               // 65536*NSEG2 float4
// flagged list overlays WS_CF (dead after scan): 65536 ints fit in 262144 floats

// ---------------- output layout ----------------
#define OUT_Q    0
#define OUT_IDX  4194304
#define OUT_CB   4259840
#define OUT_CS   4521984
#define OUT_EMA  4526080

__device__ __forceinline__ unsigned short f2bf(float f) {
    unsigned u = __float_as_uint(f);
    u += 0x7FFFu + ((u >> 16) & 1u);
    return (unsigned short)(u >> 16);
}
__device__ __forceinline__ float bf2f(unsigned short h) {
    return __uint_as_float(((unsigned)h) << 16);
}

// ---------- codebook sq-norms + bf16 hi/lo A-fragment layout (merged) ----------
// cf[ctile][frag][lane][8 shorts], frag: 0=hi k0, 1=hi k1, 2=lo k0, 3=lo k1.
// A-frag (16x16x32): lane holds A[row=lane&15][k=(lane>>4)*8 + j].
__global__ __launch_bounds__(256) void prep_all(const float* __restrict__ cb,
                                                float* __restrict__ csq,
                                                short* __restrict__ cf) {
    int k = blockIdx.x * 256 + threadIdx.x;   // 4096 threads, one code row each
    const float4* cp = (const float4*)(cb + (size_t)k * CODE_DIM);
    float rowf[64];
    float s0 = 0.f, s1 = 0.f, s2 = 0.f, s3 = 0.f;
#pragma unroll
    for (int j = 0; j < 16; ++j) {
        float4 v = cp[j];
        rowf[4*j] = v.x; rowf[4*j+1] = v.y; rowf[4*j+2] = v.z; rowf[4*j+3] = v.w;
        s0 = fmaf(v.x, v.x, s0);
        s1 = fmaf(v.y, v.y, s1);
        s2 = fmaf(v.z, v.z, s2);
        s3 = fmaf(v.w, v.w, s3);
    }
    csq[k] = (s0 + s1) + (s2 + s3);

    int ctile = k >> 4;
    int r     = k & 15;
#pragma unroll
    for (int h = 0; h < 2; ++h) {
#pragma unroll
        for (int g = 0; g < 4; ++g) {
            int lane = g * 16 + r;
            short8v H, L;
#pragma unroll
            for (int j = 0; j < 8; ++j) {
                float s = -2.0f * rowf[h * 32 + g * 8 + j];
                unsigned short hb = f2bf(s);
                H[j] = (short)hb;
                L[j] = (short)f2bf(s - bf2f(hb));
            }
            *(short8v*)(cf + ((size_t)(ctile * 4 + h) * 64 + lane) * 8)     = H;
            *(short8v*)(cf + ((size_t)(ctile * 4 + 2 + h) * 64 + lane) * 8) = L;
        }
    }
}

// ---------- MFMA scan: block = 4 waves = 4 code-segments of one 64-pt group ----------
// NOTE: min-waves launch_bounds (rounds 6/7) split the unified VGPR file and
// forced scratch spills (0.7-3 GB/dispatch). Unconstrained, the working set
// fits (~84-112 VGPR, round 3) and occupancy settles at 4-5 waves/SIMD anyway.
__global__ __launch_bounds__(256) void scan_mfma(const float* __restrict__ x,
                                                 const short* __restrict__ cf,
                                                 const float* __restrict__ csq,
                                                 float4* __restrict__ top2) {
    const int wid  = threadIdx.x >> 6;           // 0..3
    const int lane = threadIdx.x & 63;
    const int blk  = blockIdx.x;                 // 0..2047
    const int pw   = blk >> 1;                   // point group 0..1023
    const int seg  = (blk & 1) * 4 + wid;        // 0..7
    const int col  = lane & 15;
    const int grp  = lane >> 4;
    const int pbase = pw * 64;

    // B-frags for 64 points, bf16 hi/lo split in-register.
    // B-frag (16x16x32): lane holds B[k=(lane>>4)*8 + j][col=lane&15].
    short8v xh[4][2], xl[4][2];
#pragma unroll
    for (int t = 0; t < 4; ++t) {
#pragma unroll
        for (int h = 0; h < 2; ++h) {
            const float* xp = x + (size_t)(pbase + t * 16 + col) * CODE_DIM + h * 32 + grp * 8;
            float4 v0 = *(const float4*)(xp);
            float4 v1 = *(const float4*)(xp + 4);
            float f[8] = {v0.x, v0.y, v0.z, v0.w, v1.x, v1.y, v1.z, v1.w};
            short8v H, L;
#pragma unroll
            for (int j = 0; j < 8; ++j) {
                unsigned short hb = f2bf(f[j]);
                H[j] = (short)hb;
                L[j] = (short)f2bf(f[j] - bf2f(hb));
            }
            xh[t][h] = H; xl[t][h] = L;
        }
    }

    float m1[4], m2[4];
    int   i1[4];
#pragma unroll
    for (int t = 0; t < 4; ++t) { m1[t] = 3e38f; m2[t] = 3e38f; i1[t] = 0; }

#define LOAD_TILE(CT, AF, CQ) do { \
    const short* p_ = cf + ((size_t)(CT) * 4 * 64 + lane) * 8; \
    AF[0] = *(const short8v*)(p_); \
    AF[1] = *(const short8v*)(p_ + 64 * 8); \
    AF[2] = *(const short8v*)(p_ + 2 * 64 * 8); \
    AF[3] = *(const short8v*)(p_ + 3 * 64 * 8); \
    CQ = *(const float4*)(csq + (CT) * 16 + grp * 4); } while(0)

#define COMPUTE_TILE(CT, AF, CQ) do { \
    const int cbase_ = (CT) * 16 + grp * 4; \
    _Pragma("unroll") \
    for (int t = 0; t < 4; ++t) { \
        f32x4 a; a[0] = CQ.x; a[1] = CQ.y; a[2] = CQ.z; a[3] = CQ.w; \
        a = MFMA16(AF[0], xh[t][0], a, 0, 0, 0); \
        a = MFMA16(AF[1], xh[t][1], a, 0, 0, 0); \
        a = MFMA16(AF[0], xl[t][0], a, 0, 0, 0); \
        a = MFMA16(AF[1], xl[t][1], a, 0, 0, 0); \
        a = MFMA16(AF[2], xh[t][0], a, 0, 0, 0); \
        a = MFMA16(AF[3], xh[t][1], a, 0, 0, 0); \
        _Pragma("unroll") \
        for (int r = 0; r < 4; ++r) { \
            float k_ = a[r]; \
            bool lt_ = k_ < m1[t]; \
            float nm2_ = __builtin_amdgcn_fmed3f(m1[t], m2[t], k_); \
            i1[t] = lt_ ? (cbase_ + r) : i1[t]; \
            m1[t] = fminf(m1[t], k_); \
            m2[t] = nm2_; \
        } \
    } } while(0)

    short8v A0[4], A1[4];
    float4 q0, q1;
    const int tb = seg * SEGTILES;
    LOAD_TILE(tb, A0, q0);
#pragma unroll 4
    for (int it = 0; it < SEGTILES / 2; ++it) {
        const int t0 = tb + 2 * it, t1 = t0 + 1;
        const int t2 = (2 * it + 2 < SEGTILES) ? t1 + 1 : tb;
        LOAD_TILE(t1, A1, q1);
        COMPUTE_TILE(t0, A0, q0);
        LOAD_TILE(t2, A0, q0);
        COMPUTE_TILE(t1, A1, q1);
    }
#undef LOAD_TILE
#undef COMPUTE_TILE

    // cross-lane merge: lanes l, l^16, l^32 hold disjoint code subsets of point col
#pragma unroll
    for (int t = 0; t < 4; ++t) {
#pragma unroll
        for (int off = 16; off <= 32; off <<= 1) {
            float om1 = __shfl_xor(m1[t], off);
            int   oi1 = __shfl_xor(i1[t], off);
            float om2 = __shfl_xor(m2[t], off);
            float nm2 = fminf(fmaxf(m1[t], om1), fminf(m2[t], om2));
            bool take = (om1 < m1[t]) || (om1 == m1[t] && oi1 < i1[t]);
            i1[t] = take ? oi1 : i1[t];
            m1[t] = fminf(m1[t], om1);
            m2[t] = nm2;
        }
    }
    if (lane < 16) {
#pragma unroll
        for (int t = 0; t < 4; ++t) {
            top2[(size_t)(pbase + t * 16 + lane) * NSEG2 + seg] =
                make_float4(m1[t], __int_as_float(i1[t]), m2[t], 0.0f);
        }
    }
}

// ---------- merge segments; certify or flag (wave-aggregated append) ----------
__global__ __launch_bounds__(256) void emit1(const float4* __restrict__ top2,
                                             float* __restrict__ idx_out,
                                             float* __restrict__ bc_acc,
                                             int* __restrict__ flagged,
                                             int* __restrict__ cnt) {
    const int p = blockIdx.x * 256 + threadIdx.x;
    const int lane = threadIdx.x & 63;
    const float4* tp = top2 + (size_t)p * NSEG2;
    float4 t0 = tp[0];
    float m1 = t0.x; int i1 = __float_as_int(t0.y); float m2 = t0.z;
#pragma unroll
    for (int s = 1; s < NSEG2; ++s) {
        float4 t = tp[s];
        float om1 = t.x; int oi1 = __float_as_int(t.y); float om2 = t.z;
        float nm2 = fminf(fmaxf(m1, om1), fminf(m2, om2));
        bool take = (om1 < m1) || (om1 == m1 && oi1 < i1);
        if (take) i1 = oi1;
        m1 = fminf(m1, om1);
        m2 = nm2;
    }
    bool certified = (m2 - m1 >= THRF);
    if (certified) {
        idx_out[p] = (float)i1;
        atomicAdd(&bc_acc[i1], 1.0f);
    }
    // wave-aggregated flagged append: one cnt atomic per wave
    unsigned long long mask = __ballot(!certified);
    int nw = __popcll(mask);
    int base = 0;
    if (lane == 0 && nw) base = atomicAdd(cnt, nw);
    base = __shfl(base, 0);
    if (!certified) {
        int off = __popcll(mask & ((1ULL << lane) - 1ULL));
        flagged[base + off] = p;
    }
}

// ---------- exact f64 full rescan for uncertified points (wave per point) ----------
__global__ __launch_bounds__(64) void fallback_kernel(const float* __restrict__ x,
                                                      const float* __restrict__ cb,
                                                      const int* __restrict__ flagged,
                                                      const int* __restrict__ cnt,
                                                      float* __restrict__ idx_out,
                                                      float* __restrict__ bc_acc) {
    __shared__ float xs[CODE_DIM];
    const int lane = threadIdx.x;
    const int n = *cnt;
    for (int w = blockIdx.x; w < n; w += 1024) {
        const int p = flagged[w];
        xs[lane] = x[(size_t)p * CODE_DIM + lane];
        __syncthreads();
        float4 xv[16];
#pragma unroll
        for (int q = 0; q < 16; ++q) xv[q] = *(const float4*)(xs + q * 4);
        double best = 1e300; int bi = 0;
        for (int j = 0; j < 64; ++j) {
            const int c = lane + 64 * j;   // ascending per lane
            const float4* cp = (const float4*)(cb + (size_t)c * CODE_DIM);
            double a0 = 0.0, a1 = 0.0, a2 = 0.0, a3 = 0.0;
#pragma unroll
            for (int q = 0; q < 16; ++q) {
                float4 cv = cp[q];
                double d0 = (double)xv[q].x - (double)cv.x;
                double d1 = (double)xv[q].y - (double)cv.y;
                double d2 = (double)xv[q].z - (double)cv.z;
                double d3 = (double)xv[q].w - (double)cv.w;
                a0 = fma(d0, d0, a0);
                a1 = fma(d1, d1, a1);
                a2 = fma(d2, d2, a2);
                a3 = fma(d3, d3, a3);
            }
            double acc = (a0 + a1) + (a2 + a3);
            if (acc < best) { best = acc; bi = c; }
        }
#pragma unroll
        for (int off = 1; off < 64; off <<= 1) {
            double ob = __shfl_xor(best, off);
            int   obi = __shfl_xor(bi, off);
            if (ob < best || (ob == best && obi < bi)) { best = ob; bi = obi; }
        }
        if (lane == 0) {
            idx_out[p] = (float)bi;
            atomicAdd(&bc_acc[bi], 1.0f);
        }
        __syncthreads();
    }
}

// ---------- quantized write + embed_sum scatter: one wave per point ----------
__global__ __launch_bounds__(256) void emit2(const float* __restrict__ x,
                                             const float* __restrict__ cb,
                                             const float* __restrict__ idx_out,
                                             float* __restrict__ q_out,
                                             float* __restrict__ es_acc) {
    const int p    = blockIdx.x * 4 + (threadIdx.x >> 6);
    const int lane = threadIdx.x & 63;
    const int fin  = (int)idx_out[p];
    float xv = x[(size_t)p * CODE_DIM + lane];
    float cv = cb[(size_t)fin * CODE_DIM + lane];
    q_out[(size_t)p * CODE_DIM + lane] = cv;
    atomicAdd(&es_acc[(size_t)fin * CODE_DIM + lane], xv);
}

__global__ __launch_bounds__(256) void ncs_kernel(const float* __restrict__ cs_in,
                                                  const float* __restrict__ bc_acc,
                                                  float* __restrict__ cs_out,
                                                  float* __restrict__ n_acc) {
    int k = blockIdx.x * 256 + threadIdx.x;   // 4096 threads
    float v = DECAYF * cs_in[k] + (1.0f - DECAYF) * bc_acc[k];
    cs_out[k] = v;
    float s = v;
#pragma unroll
    for (int off = 32; off > 0; off >>= 1) s += __shfl_down(s, off);
    if ((threadIdx.x & 63) == 0) atomicAdd(n_acc, s);
}

__global__ __launch_bounds__(256) void finalize_kernel(const float* __restrict__ ema_in,
                                                       const float* __restrict__ es_acc,
                                                       const float* __restrict__ cs_out,
                                                       const float* __restrict__ n_acc,
                                                       float* __restrict__ ema_out,
                                                       float* __restrict__ cb_out) {
    int idx = blockIdx.x * 256 + threadIdx.x;   // 262144 threads
    int k   = idx >> 6;
    float n = *n_acc;
    float ncs = cs_out[k];
    float smoothed = (ncs + EPSF) / (n + (float)NUM_CODES * EPSF) * n;
    float ew = DECAYF * ema_in[idx] + (1.0f - DECAYF) * es_acc[idx];
    ema_out[idx] = ew;
    cb_out[idx]  = ew / smoothed;
}

extern "C" void kernel_launch(void* const* d_in, const int* in_sizes, int n_in,
                              void* d_out, int out_size, void* d_ws, size_t ws_size,
                              hipStream_t stream) {
    const float* x    = (const float*)d_in[0];
    const float* cb   = (const float*)d_in[1];
    const float* cs   = (const float*)d_in[2];
    const float* emaw = (const float*)d_in[3];
    float* out = (float*)d_out;
    float* ws  = (float*)d_ws;

    // zero bc + es + n + cnt (contiguous)
    hipMemsetAsync(ws, 0, (size_t)(WS_CNT + 1) * sizeof(float), stream);

    prep_all<<<NUM_CODES / 256, 256, 0, stream>>>(cb, ws + WS_CSQ, (short*)(ws + WS_CF));

    scan_mfma<<<(NPTS / 64) * NSEG2 / 4, 256, 0, stream>>>(
        x, (const short*)(ws + WS_CF), ws + WS_CSQ, (float4*)(ws + WS_TOP2));

    emit1<<<NPTS / 256, 256, 0, stream>>>(
        (const float4*)(ws + WS_TOP2), out + OUT_IDX, ws + WS_BC,
        (int*)(ws + WS_CF), (int*)(ws + WS_CNT));

    fallback_kernel<<<1024, 64, 0, stream>>>(
        x, cb, (const int*)(ws + WS_CF), (const int*)(ws + WS_CNT),
        out + OUT_IDX, ws + WS_BC);

    emit2<<<NPTS / 4, 256, 0, stream>>>(
        x, cb, out + OUT_IDX, out + OUT_Q, ws + WS_ES);

    ncs_kernel<<<NUM_CODES / 256, 256, 0, stream>>>(
        cs, ws + WS_BC, out + OUT_CS, ws + WS_N);

    finalize_kernel<<<(NUM_CODES * CODE_DIM) / 256, 256, 0, stream>>>(
        emaw, ws + WS_ES, out + OUT_CS, ws + WS_N, out + OUT_EMA, out + OUT_CB);
}

// Round 10
// 310.356 us; speedup vs baseline: 3.0540x; 1.0731x over previous
//
#include <hip/hip_runtime.h>

#define NUM_CODES 4096
#define CODE_DIM  64
#define NPTS      65536              // B*S = 16*4096
#define NTILES    (NUM_CODES / 16)   // 256 code tiles
#define NSEG2     8                  // code segments in scan
#define SEGTILES  (NTILES / NSEG2)   // 32 tiles per segment
#define NCOPY     8                  // XCD-local accumulator copies
#define DECAYF    0.99f
#define EPSF      1e-5f
#define BIASF     512.0f             // makes all packed distances positive
#define THRF      0.0625f            // certify threshold (quantum .031 + mfma err 3e-3)

typedef __attribute__((ext_vector_type(8))) short short8v;
typedef __attribute__((ext_vector_type(4))) float f32x4;
#define MFMA16 __builtin_amdgcn_mfma_f32_16x16x32_bf16

__device__ __forceinline__ unsigned med3u(unsigned a, unsigned b, unsigned c) {
    unsigned d;
    asm("v_med3_u32 %0, %1, %2, %3" : "=v"(d) : "v"(a), "v"(b), "v"(c));
    return d;
}
__device__ __forceinline__ unsigned min3u(unsigned a, unsigned b, unsigned c) {
    unsigned d;
    asm("v_min3_u32 %0, %1, %2, %3" : "=v"(d) : "v"(a), "v"(b), "v"(c));
    return d;
}
__device__ __forceinline__ unsigned minu(unsigned a, unsigned b) { return a < b ? a : b; }
__device__ __forceinline__ unsigned maxu(unsigned a, unsigned b) { return a > b ? a : b; }

// ---------------- workspace layout (float indices) ----------------
#define WS_BC   0                        // 8 x 4096 batch_cluster copies
#define WS_ES   32768                    // 8 x 262144 embed_sum copies
#define WS_N    2129920                  // 1  n (precomputed)
#define WS_CNT  2129921                  // 1  flagged count (int)
#define WS_CSQ  2129924                  // 4096 csq+BIAS (16B aligned)
#define WS_CF   2134020                  // 262144 floats A-frag codebook (16B aligned)
#define WS_TOP2 2396164                  // 8 segs x 65536 uint2 (= 1048576 floats)
// flagged list overlays WS_CF (dead after scan)

// ---------------- output layout ----------------
#define OUT_Q    0
#define OUT_IDX  4194304
#define OUT_CB   4259840
#define OUT_CS   4521984
#define OUT_EMA  4526080

__device__ __forceinline__ unsigned short f2bf(float f) {
    unsigned u = __float_as_uint(f);
    u += 0x7FFFu + ((u >> 16) & 1u);
    return (unsigned short)(u >> 16);
}
__device__ __forceinline__ float bf2f(unsigned short h) {
    return __uint_as_float(((unsigned)h) << 16);
}

// ---------- prep: csq(+bias) + bf16 hi/lo A-frags + n scalar ----------
// blocks 0..127: thread = (code, chunk8): chunk -> khalf=chunk>>2, g=chunk&3
// block 128: n = 0.99*sum(cs_in) + 0.01*NPTS
__global__ __launch_bounds__(256) void prep_all(const float* __restrict__ cb,
                                                const float* __restrict__ cs_in,
                                                float* __restrict__ csq,
                                                short* __restrict__ cf,
                                                float* __restrict__ n_out) {
    if (blockIdx.x == 128) {
        __shared__ float ws4[4];
        int tid = threadIdx.x;
        float s = 0.f;
#pragma unroll
        for (int j = 0; j < 16; ++j) s += cs_in[tid + 256 * j];
#pragma unroll
        for (int off = 32; off > 0; off >>= 1) s += __shfl_down(s, off);
        if ((tid & 63) == 0) ws4[tid >> 6] = s;
        __syncthreads();
        if (tid == 0)
            n_out[0] = DECAYF * (ws4[0] + ws4[1] + ws4[2] + ws4[3])
                     + (1.0f - DECAYF) * (float)NPTS;
        return;
    }
    int t     = blockIdx.x * 256 + threadIdx.x;   // 32768 threads
    int code  = t >> 3;
    int chunk = t & 7;
    int khalf = chunk >> 2;
    int g     = chunk & 3;
    const float* src = cb + (size_t)code * CODE_DIM + khalf * 32 + g * 8;
    float4 v0 = *(const float4*)(src);
    float4 v1 = *(const float4*)(src + 4);
    float f[8] = {v0.x, v0.y, v0.z, v0.w, v1.x, v1.y, v1.z, v1.w};
    float sq = 0.f;
    short8v H, L;
#pragma unroll
    for (int j = 0; j < 8; ++j) {
        sq = fmaf(f[j], f[j], sq);
        float s = -2.0f * f[j];
        unsigned short hb = f2bf(s);
        H[j] = (short)hb;
        L[j] = (short)f2bf(s - bf2f(hb));
    }
#pragma unroll
    for (int off = 1; off < 8; off <<= 1) sq += __shfl_xor(sq, off);
    if (chunk == 0) csq[code] = sq + BIASF;
    int ctile = code >> 4;
    int lane_in_frag = g * 16 + (code & 15);
    *(short8v*)(cf + ((size_t)(ctile * 4 + khalf) * 64 + lane_in_frag) * 8)     = H;
    *(short8v*)(cf + ((size_t)(ctile * 4 + 2 + khalf) * 64 + lane_in_frag) * 8) = L;
}

// ---------- MFMA scan: block = 4 waves = 4 code-segments of one 64-pt group ----------
// Fold: u32 packed keys (biased f32 bits | 9-bit lane-local index tile:5|grp:2|r:2)
__global__ __launch_bounds__(256) void scan_mfma(const float* __restrict__ x,
                                                 const short* __restrict__ cf,
                                                 const float* __restrict__ csq,
                                                 uint2* __restrict__ top2) {
    const int wid  = threadIdx.x >> 6;           // 0..3
    const int lane = threadIdx.x & 63;
    const int blk  = blockIdx.x;                 // 0..2047
    const int pw   = blk >> 1;                   // point group 0..1023
    const int seg  = (blk & 1) * 4 + wid;        // 0..7
    const int col  = lane & 15;
    const int grp  = lane >> 4;
    const unsigned grpsh = (unsigned)(grp << 2);
    const int pbase = pw * 64;

    // B-frags for 64 points, bf16 hi/lo split in-register.
    short8v xh[4][2], xl[4][2];
#pragma unroll
    for (int t = 0; t < 4; ++t) {
#pragma unroll
        for (int h = 0; h < 2; ++h) {
            const float* xp = x + (size_t)(pbase + t * 16 + col) * CODE_DIM + h * 32 + grp * 8;
            float4 v0 = *(const float4*)(xp);
            float4 v1 = *(const float4*)(xp + 4);
            float f[8] = {v0.x, v0.y, v0.z, v0.w, v1.x, v1.y, v1.z, v1.w};
            short8v H, L;
#pragma unroll
            for (int j = 0; j < 8; ++j) {
                unsigned short hb = f2bf(f[j]);
                H[j] = (short)hb;
                L[j] = (short)f2bf(f[j] - bf2f(hb));
            }
            xh[t][h] = H; xl[t][h] = L;
        }
    }

    unsigned m1k[4], m2k[4];
#pragma unroll
    for (int t = 0; t < 4; ++t) { m1k[t] = 0xFFFFFFFFu; m2k[t] = 0xFFFFFFFFu; }

#define LOAD_TILE(CT, AF, CQ) do { \
    const short* p_ = cf + ((size_t)(CT) * 4 * 64 + lane) * 8; \
    AF[0] = *(const short8v*)(p_); \
    AF[1] = *(const short8v*)(p_ + 64 * 8); \
    AF[2] = *(const short8v*)(p_ + 2 * 64 * 8); \
    AF[3] = *(const short8v*)(p_ + 3 * 64 * 8); \
    CQ = *(const f32x4*)(csq + (CT) * 16 + grp * 4); } while(0)

#define COMPUTE_TILE(CT, AF, CQ) do { \
    const unsigned tb9_ = (unsigned)(((CT) - tb) << 4) | grpsh; \
    unsigned idx_[4] = {tb9_, tb9_ | 1u, tb9_ | 2u, tb9_ | 3u}; \
    _Pragma("unroll") \
    for (int t = 0; t < 4; ++t) { \
        f32x4 a = CQ; \
        a = MFMA16(AF[0], xh[t][0], a, 0, 0, 0); \
        a = MFMA16(AF[1], xh[t][1], a, 0, 0, 0); \
        a = MFMA16(AF[0], xl[t][0], a, 0, 0, 0); \
        a = MFMA16(AF[1], xl[t][1], a, 0, 0, 0); \
        a = MFMA16(AF[2], xh[t][0], a, 0, 0, 0); \
        a = MFMA16(AF[3], xh[t][1], a, 0, 0, 0); \
        _Pragma("unroll") \
        for (int r = 0; r < 4; ++r) { \
            unsigned key = (__float_as_uint(a[r]) & 0xFFFFFE00u) | idx_[r]; \
            m2k[t] = med3u(m1k[t], m2k[t], key); \
            m1k[t] = minu(m1k[t], key); \
        } \
    } } while(0)

    short8v A0[4], A1[4];
    f32x4 q0, q1;
    const int tb = seg * SEGTILES;
    LOAD_TILE(tb, A0, q0);
#pragma unroll 4
    for (int it = 0; it < SEGTILES / 2; ++it) {
        const int t0 = tb + 2 * it, t1 = t0 + 1;
        const int t2 = (2 * it + 2 < SEGTILES) ? t1 + 1 : tb;
        LOAD_TILE(t1, A1, q1);
        COMPUTE_TILE(t0, A0, q0);
        LOAD_TILE(t2, A0, q0);
        COMPUTE_TILE(t1, A1, q1);
    }
#undef LOAD_TILE
#undef COMPUTE_TILE

    // cross-lane merge (keys carry index & code-order tie-break)
#pragma unroll
    for (int t = 0; t < 4; ++t) {
#pragma unroll
        for (int off = 16; off <= 32; off <<= 1) {
            unsigned o1 = __shfl_xor(m1k[t], off);
            unsigned o2 = __shfl_xor(m2k[t], off);
            m2k[t] = min3u(maxu(m1k[t], o1), m2k[t], o2);
            m1k[t] = minu(m1k[t], o1);
        }
    }
    if (lane < 16) {
#pragma unroll
        for (int t = 0; t < 4; ++t)
            top2[(size_t)seg * NPTS + pbase + t * 16 + lane] = make_uint2(m1k[t], m2k[t]);
    }
}

// ---------- merge segments; certify or flag (wave-aggregated append) ----------
__global__ __launch_bounds__(256) void emit1(const uint2* __restrict__ top2,
                                             float* __restrict__ idx_out,
                                             float* __restrict__ bc_acc,
                                             int* __restrict__ flagged,
                                             int* __restrict__ cnt) {
    const int p = blockIdx.x * 256 + threadIdx.x;
    const int lane = threadIdx.x & 63;
    unsigned M1 = 0xFFFFFFFFu, M2 = 0xFFFFFFFFu;
    int wseg = 0;
#pragma unroll
    for (int s = 0; s < NSEG2; ++s) {
        uint2 t = top2[(size_t)s * NPTS + p];
        M2 = min3u(maxu(M1, t.x), M2, t.y);
        if (t.x < M1) wseg = s;
        M1 = minu(M1, t.x);
    }
    float m1v = __uint_as_float(M1 & 0xFFFFFE00u);
    float m2v = __uint_as_float(M2 & 0xFFFFFE00u);
    unsigned bits = M1 & 0x1FFu;
    int code = (wseg * SEGTILES + (int)(bits >> 4)) * 16 + (int)((bits >> 2) & 3u) * 4 + (int)(bits & 3u);

    bool certified = (m2v - m1v >= THRF);
    if (certified) {
        idx_out[p] = (float)code;
        atomicAdd(&bc_acc[(blockIdx.x & (NCOPY - 1)) * NUM_CODES + code], 1.0f);
    }
    unsigned long long mask = __ballot(!certified);
    int nw = __popcll(mask);
    int base = 0;
    if (lane == 0 && nw) base = atomicAdd(cnt, nw);
    base = __shfl(base, 0);
    if (!certified) {
        int off = __popcll(mask & ((1ULL << lane) - 1ULL));
        flagged[base + off] = p;
    }
}

// ---------- exact f64 full rescan for uncertified points (wave per point) ----------
__global__ __launch_bounds__(64) void fallback_kernel(const float* __restrict__ x,
                                                      const float* __restrict__ cb,
                                                      const int* __restrict__ flagged,
                                                      const int* __restrict__ cnt,
                                                      float* __restrict__ idx_out,
                                                      float* __restrict__ bc_acc) {
    __shared__ float xs[CODE_DIM];
    const int lane = threadIdx.x;
    const int n = *cnt;
    float* bcc = bc_acc + (size_t)(blockIdx.x & (NCOPY - 1)) * NUM_CODES;
    for (int w = blockIdx.x; w < n; w += 1024) {
        const int p = flagged[w];
        xs[lane] = x[(size_t)p * CODE_DIM + lane];
        __syncthreads();
        float4 xv[16];
#pragma unroll
        for (int q = 0; q < 16; ++q) xv[q] = *(const float4*)(xs + q * 4);
        double best = 1e300; int bi = 0;
        for (int j = 0; j < 64; ++j) {
            const int c = lane + 64 * j;
            const float4* cp = (const float4*)(cb + (size_t)c * CODE_DIM);
            double a0 = 0.0, a1 = 0.0, a2 = 0.0, a3 = 0.0;
#pragma unroll
            for (int q = 0; q < 16; ++q) {
                float4 cv = cp[q];
                double d0 = (double)xv[q].x - (double)cv.x;
                double d1 = (double)xv[q].y - (double)cv.y;
                double d2 = (double)xv[q].z - (double)cv.z;
                double d3 = (double)xv[q].w - (double)cv.w;
                a0 = fma(d0, d0, a0);
                a1 = fma(d1, d1, a1);
                a2 = fma(d2, d2, a2);
                a3 = fma(d3, d3, a3);
            }
            double acc = (a0 + a1) + (a2 + a3);
            if (acc < best) { best = acc; bi = c; }
        }
#pragma unroll
        for (int off = 1; off < 64; off <<= 1) {
            double ob = __shfl_xor(best, off);
            int   obi = __shfl_xor(bi, off);
            if (ob < best || (ob == best && obi < bi)) { best = ob; bi = obi; }
        }
        if (lane == 0) {
            idx_out[p] = (float)bi;
            atomicAdd(&bcc[bi], 1.0f);
        }
        __syncthreads();
    }
}

// ---------- quantized write + embed_sum scatter (XCD-local copy) ----------
__global__ __launch_bounds__(256) void emit2(const float* __restrict__ x,
                                             const float* __restrict__ cb,
                                             const float* __restrict__ idx_out,
                                             float* __restrict__ q_out,
                                             float* __restrict__ es_acc) {
    const int p    = blockIdx.x * 4 + (threadIdx.x >> 6);
    const int lane = threadIdx.x & 63;
    const int fin  = (int)idx_out[p];
    float* esc = es_acc + (size_t)(blockIdx.x & (NCOPY - 1)) * (NUM_CODES * CODE_DIM);
    float xv = x[(size_t)p * CODE_DIM + lane];
    float cv = cb[(size_t)fin * CODE_DIM + lane];
    q_out[(size_t)p * CODE_DIM + lane] = cv;
    atomicAdd(&esc[(size_t)fin * CODE_DIM + lane], xv);
}

// ---------- finalize: sum copies, EMA, smoothed codebook, cs ----------
__global__ __launch_bounds__(256) void finalize_kernel(const float* __restrict__ cs_in,
                                                       const float* __restrict__ ema_in,
                                                       const float* __restrict__ bc_acc,
                                                       const float* __restrict__ es_acc,
                                                       const float* __restrict__ n_ptr,
                                                       float* __restrict__ cs_out,
                                                       float* __restrict__ ema_out,
                                                       float* __restrict__ cb_out) {
    int idx = blockIdx.x * 256 + threadIdx.x;   // 262144 threads
    int k   = idx >> 6;
    float bc = 0.f, es = 0.f;
#pragma unroll
    for (int c = 0; c < NCOPY; ++c) {
        bc += bc_acc[(size_t)c * NUM_CODES + k];
        es += es_acc[(size_t)c * (NUM_CODES * CODE_DIM) + idx];
    }
    float ncs = DECAYF * cs_in[k] + (1.0f - DECAYF) * bc;
    if ((idx & 63) == 0) cs_out[k] = ncs;
    float n = *n_ptr;
    float smoothed = (ncs + EPSF) / (n + (float)NUM_CODES * EPSF) * n;
    float ew = DECAYF * ema_in[idx] + (1.0f - DECAYF) * es;
    ema_out[idx] = ew;
    cb_out[idx]  = ew / smoothed;
}

extern "C" void kernel_launch(void* const* d_in, const int* in_sizes, int n_in,
                              void* d_out, int out_size, void* d_ws, size_t ws_size,
                              hipStream_t stream) {
    const float* x    = (const float*)d_in[0];
    const float* cb   = (const float*)d_in[1];
    const float* cs   = (const float*)d_in[2];
    const float* emaw = (const float*)d_in[3];
    float* out = (float*)d_out;
    float* ws  = (float*)d_ws;

    // zero bc copies + es copies + n + cnt (contiguous)
    hipMemsetAsync(ws, 0, (size_t)(WS_CNT + 1) * sizeof(float), stream);

    prep_all<<<129, 256, 0, stream>>>(cb, cs, ws + WS_CSQ, (short*)(ws + WS_CF), ws + WS_N);

    scan_mfma<<<(NPTS / 64) * NSEG2 / 4, 256, 0, stream>>>(
        x, (const short*)(ws + WS_CF), ws + WS_CSQ, (uint2*)(ws + WS_TOP2));

    emit1<<<NPTS / 256, 256, 0, stream>>>(
        (const uint2*)(ws + WS_TOP2), out + OUT_IDX, ws + WS_BC,
        (int*)(ws + WS_CF), (int*)(ws + WS_CNT));

    fallback_kernel<<<1024, 64, 0, stream>>>(
        x, cb, (const int*)(ws + WS_CF), (const int*)(ws + WS_CNT),
        out + OUT_IDX, ws + WS_BC);

    emit2<<<NPTS / 4, 256, 0, stream>>>(
        x, cb, out + OUT_IDX, out + OUT_Q, ws + WS_ES);

    finalize_kernel<<<(NUM_CODES * CODE_DIM) / 256, 256, 0, stream>>>(
        cs, emaw, ws + WS_BC, ws + WS_ES, ws + WS_N,
        out + OUT_CS, out + OUT_EMA, out + OUT_CB);
}